// Round 1
// baseline (197.491 us; speedup 1.0000x reference)
//
#include <hip/hip_runtime.h>

#define ROW_LEN 4096
#define BLOCK 256
#define PER_THREAD 16   // ROW_LEN / BLOCK

__global__ __launch_bounds__(BLOCK) void row_cumsum_kernel(
    const float* __restrict__ in, float* __restrict__ out) {
    const size_t row = blockIdx.x;
    const float* src = in + row * (size_t)ROW_LEN;
    float* dst = out + row * (size_t)ROW_LEN;
    const int t = threadIdx.x;

    // Load 16 contiguous floats per thread as 4x float4.
    const float4* s4 = reinterpret_cast<const float4*>(src + t * PER_THREAD);
    float4 a = s4[0];
    float4 b = s4[1];
    float4 c = s4[2];
    float4 d = s4[3];

    float v[PER_THREAD];
    v[0]  = a.x; v[1]  = a.y; v[2]  = a.z; v[3]  = a.w;
    v[4]  = b.x; v[5]  = b.y; v[6]  = b.z; v[7]  = b.w;
    v[8]  = c.x; v[9]  = c.y; v[10] = c.z; v[11] = c.w;
    v[12] = d.x; v[13] = d.y; v[14] = d.z; v[15] = d.w;

    // In-register inclusive scan of this thread's chunk.
    #pragma unroll
    for (int i = 1; i < PER_THREAD; ++i) v[i] += v[i - 1];
    const float total = v[PER_THREAD - 1];

    // Wave-level (64-lane) inclusive scan of thread totals.
    const int lane = t & 63;
    const int wave = t >> 6;
    float x = total;
    #pragma unroll
    for (int off = 1; off < 64; off <<= 1) {
        float y = __shfl_up(x, off, 64);
        if (lane >= off) x += y;
    }

    // Combine the 4 wave sums via LDS.
    __shared__ float wsum[BLOCK / 64];
    if (lane == 63) wsum[wave] = x;
    __syncthreads();
    float wexcl = 0.0f;
    #pragma unroll
    for (int w = 0; w < BLOCK / 64; ++w) {
        if (w < wave) wexcl += wsum[w];
    }

    // Exclusive prefix for this thread's chunk.
    const float excl = wexcl + (x - total);
    #pragma unroll
    for (int i = 0; i < PER_THREAD; ++i) v[i] += excl;

    float4* d4 = reinterpret_cast<float4*>(dst + t * PER_THREAD);
    d4[0] = make_float4(v[0],  v[1],  v[2],  v[3]);
    d4[1] = make_float4(v[4],  v[5],  v[6],  v[7]);
    d4[2] = make_float4(v[8],  v[9],  v[10], v[11]);
    d4[3] = make_float4(v[12], v[13], v[14], v[15]);
}

extern "C" void kernel_launch(void* const* d_in, const int* in_sizes, int n_in,
                              void* d_out, int out_size, void* d_ws, size_t ws_size,
                              hipStream_t stream) {
    const float* x = (const float*)d_in[0];
    float* out = (float*)d_out;
    const int n_rows = in_sizes[0] / ROW_LEN;  // 8*4096 = 32768
    row_cumsum_kernel<<<n_rows, BLOCK, 0, stream>>>(x, out);
}

// Round 2
// 193.665 us; speedup vs baseline: 1.0198x; 1.0198x over previous
//
#include <hip/hip_runtime.h>

#define ROW_LEN 4096
#define BLOCK 256
#define SEGS 4
#define SEG_LEN 1024   // ROW_LEN / SEGS
#define NWAVES 4       // BLOCK / 64

__global__ __launch_bounds__(BLOCK) void row_cumsum_kernel(
    const float* __restrict__ in, float* __restrict__ out) {
    const size_t row = blockIdx.x;
    const float* src = in + row * (size_t)ROW_LEN;
    float* dst = out + row * (size_t)ROW_LEN;
    const int t = threadIdx.x;
    const int lane = t & 63;
    const int wave = t >> 6;

    // Each load instruction reads a contiguous 1KB span per wave:
    // thread t owns float4 #t of each 1024-float segment.
    float4 seg[SEGS];
    #pragma unroll
    for (int s = 0; s < SEGS; ++s)
        seg[s] = reinterpret_cast<const float4*>(src + s * SEG_LEN)[t];

    // In-thread inclusive scan within each float4; wave-scan the totals.
    float tot[SEGS], x[SEGS];
    #pragma unroll
    for (int s = 0; s < SEGS; ++s) {
        seg[s].y += seg[s].x;
        seg[s].z += seg[s].y;
        seg[s].w += seg[s].z;
        tot[s] = seg[s].w;
        x[s] = tot[s];
        #pragma unroll
        for (int off = 1; off < 64; off <<= 1) {
            float y = __shfl_up(x[s], off, 64);
            if (lane >= off) x[s] += y;
        }
    }

    // Cross-wave + cross-segment combine via a 16-entry LDS table.
    __shared__ float wsum[SEGS][NWAVES];
    if (lane == 63) {
        #pragma unroll
        for (int s = 0; s < SEGS; ++s) wsum[s][wave] = x[s];
    }
    __syncthreads();

    float prevseg = 0.0f;  // total of all segments before s
    #pragma unroll
    for (int s = 0; s < SEGS; ++s) {
        float waveexcl = 0.0f, segtot = 0.0f;
        #pragma unroll
        for (int w = 0; w < NWAVES; ++w) {
            float v = wsum[s][w];
            segtot += v;
            if (w < wave) waveexcl += v;
        }
        const float excl = prevseg + waveexcl + (x[s] - tot[s]);
        seg[s].x += excl;
        seg[s].y += excl;
        seg[s].z += excl;
        seg[s].w += excl;
        prevseg += segtot;
    }

    // Contiguous 1KB-per-wave stores.
    #pragma unroll
    for (int s = 0; s < SEGS; ++s)
        reinterpret_cast<float4*>(dst + s * SEG_LEN)[t] = seg[s];
}

extern "C" void kernel_launch(void* const* d_in, const int* in_sizes, int n_in,
                              void* d_out, int out_size, void* d_ws, size_t ws_size,
                              hipStream_t stream) {
    const float* x = (const float*)d_in[0];
    float* out = (float*)d_out;
    const int n_rows = in_sizes[0] / ROW_LEN;  // 32768
    row_cumsum_kernel<<<n_rows, BLOCK, 0, stream>>>(x, out);
}

// Round 4
// 180.317 us; speedup vs baseline: 1.0952x; 1.0740x over previous
//
#include <hip/hip_runtime.h>

#define ROW_LEN 4096
#define BLOCK 256
#define SEGS 4
#define SEG_LEN 1024   // ROW_LEN / SEGS
#define NWAVES 4       // BLOCK / 64

typedef float f32x4 __attribute__((ext_vector_type(4)));

__global__ __launch_bounds__(BLOCK) void row_cumsum_kernel(
    const float* __restrict__ in, float* __restrict__ out) {
    const size_t row = blockIdx.x;
    const float* src = in + row * (size_t)ROW_LEN;
    float* dst = out + row * (size_t)ROW_LEN;
    const int t = threadIdx.x;
    const int lane = t & 63;
    const int wave = t >> 6;

    // Streaming (nontemporal) loads: data is touched exactly once.
    f32x4 seg[SEGS];
    #pragma unroll
    for (int s = 0; s < SEGS; ++s)
        seg[s] = __builtin_nontemporal_load(
            reinterpret_cast<const f32x4*>(src + s * SEG_LEN) + t);

    // In-thread inclusive scan within each float4; wave-scan the totals.
    float tot[SEGS], x[SEGS];
    #pragma unroll
    for (int s = 0; s < SEGS; ++s) {
        seg[s].y += seg[s].x;
        seg[s].z += seg[s].y;
        seg[s].w += seg[s].z;
        tot[s] = seg[s].w;
        x[s] = tot[s];
        #pragma unroll
        for (int off = 1; off < 64; off <<= 1) {
            float y = __shfl_up(x[s], off, 64);
            if (lane >= off) x[s] += y;
        }
    }

    // Cross-wave + cross-segment combine via a 16-entry LDS table.
    __shared__ float wsum[SEGS][NWAVES];
    if (lane == 63) {
        #pragma unroll
        for (int s = 0; s < SEGS; ++s) wsum[s][wave] = x[s];
    }
    __syncthreads();

    float prevseg = 0.0f;  // total of all segments before s
    #pragma unroll
    for (int s = 0; s < SEGS; ++s) {
        float waveexcl = 0.0f, segtot = 0.0f;
        #pragma unroll
        for (int w = 0; w < NWAVES; ++w) {
            float v = wsum[s][w];
            segtot += v;
            if (w < wave) waveexcl += v;
        }
        const float excl = prevseg + waveexcl + (x[s] - tot[s]);
        seg[s].x += excl;
        seg[s].y += excl;
        seg[s].z += excl;
        seg[s].w += excl;
        prevseg += segtot;
    }

    // Streaming stores, contiguous 1KB per wave instruction.
    #pragma unroll
    for (int s = 0; s < SEGS; ++s)
        __builtin_nontemporal_store(seg[s],
            reinterpret_cast<f32x4*>(dst + s * SEG_LEN) + t);
}

extern "C" void kernel_launch(void* const* d_in, const int* in_sizes, int n_in,
                              void* d_out, int out_size, void* d_ws, size_t ws_size,
                              hipStream_t stream) {
    const float* x = (const float*)d_in[0];
    float* out = (float*)d_out;
    const int n_rows = in_sizes[0] / ROW_LEN;  // 32768
    row_cumsum_kernel<<<n_rows, BLOCK, 0, stream>>>(x, out);
}